// Round 2
// baseline (142.868 us; speedup 1.0000x reference)
//
#include <hip/hip_runtime.h>
#include <hip/hip_bf16.h>

// Shapes (compile-time constants from the reference)
#define B_ 64
#define L_ 64
#define D_ 512
#define F_ 32
#define H_ 512
// A = [f1 | m1] : (B*F_) x (2*D) = 2048 x 1024
#define M_ROWS 2048
#define KA 1024

__device__ __forceinline__ float leaky(float v) { return v > 0.0f ? v : 0.01f * v; }

// Kernel 1: gather f1 rows, compute m1 = mean of 32 gathered rows (idx2), and
// m0 = mean of 32 gathered rows (idx1). Packs A[r] = [f1_r (512) | m1_r (512)].
// grid: 2048 + 64 blocks, 128 threads.
__global__ __launch_bounds__(128) void gather_pack(
    const float* __restrict__ x, const int* __restrict__ idx1,
    const int* __restrict__ idx2, float* __restrict__ A, float* __restrict__ m0) {
  int blk = blockIdx.x;
  int t = threadIdx.x;  // 0..127, handles float4 at col t*4
  if (blk < M_ROWS) {
    int b = blk >> 5;
    int f = blk & 31;
    const float* xb = x + (size_t)b * L_ * D_;
    // f1 row copy
    int r1 = idx1[b * F_ + f];
    float4 v = *(const float4*)(xb + (size_t)r1 * D_ + t * 4);
    float* Arow = A + (size_t)blk * KA;
    *(float4*)(Arow + t * 4) = v;
    // m1 = mean of 32 idx2-gathered rows
    const int* id2 = idx2 + b * F_ * F_ + f * F_;
    float4 acc = make_float4(0.f, 0.f, 0.f, 0.f);
#pragma unroll 4
    for (int j = 0; j < 32; ++j) {
      int r = id2[j];
      float4 w = *(const float4*)(xb + (size_t)r * D_ + t * 4);
      acc.x += w.x; acc.y += w.y; acc.z += w.z; acc.w += w.w;
    }
    const float s = 1.0f / 32.0f;
    acc.x *= s; acc.y *= s; acc.z *= s; acc.w *= s;
    *(float4*)(Arow + D_ + t * 4) = acc;
  } else {
    int b = blk - M_ROWS;  // 0..63
    const float* xb = x + (size_t)b * L_ * D_;
    const int* id1 = idx1 + b * F_;
    float4 acc = make_float4(0.f, 0.f, 0.f, 0.f);
#pragma unroll 4
    for (int j = 0; j < 32; ++j) {
      int r = id1[j];
      float4 w = *(const float4*)(xb + (size_t)r * D_ + t * 4);
      acc.x += w.x; acc.y += w.y; acc.z += w.z; acc.w += w.w;
    }
    const float s = 1.0f / 32.0f;
    acc.x *= s; acc.y *= s; acc.z *= s; acc.w *= s;
    *(float4*)(m0 + (size_t)b * D_ + t * 4) = acc;
  }
}

// Kernel 2: h1_partial[z] = A[:, z*256:(z+1)*256] @ W[z-part]
// z=0,1 -> f1 cols with W_self0 rows; z=2,3 -> m1 cols with W_aggr0 rows.
// 128x128 tile, 8x8 micro-tile, 256 threads, BK=16, 16 k-tiles per block.
// grid (16, 4, 4). Bias + leaky deferred to out_kernel (keeps partials exact).
__global__ __launch_bounds__(256) void gemm_h1(
    const float* __restrict__ A, const float* __restrict__ Ws0,
    const float* __restrict__ Wa0, float* __restrict__ h1p) {
  __shared__ float As[16][132];
  __shared__ float Bs[16][132];
  const int tid = threadIdx.x;
  const int bm = blockIdx.x * 128;
  const int bn = blockIdx.y * 128;
  const int z = blockIdx.z;
  const float* Wbase = (z < 2) ? Ws0 : Wa0;
  const int kA0 = z * 256;        // col offset into A
  const int kW0 = (z & 1) * 256;  // row offset into W half

  // loader coords
  const int arow = tid >> 1;          // 0..127
  const int akl = (tid & 1) * 8;      // 0 or 8
  const int bkrow = tid >> 4;         // 0..15
  const int bnc = (tid & 15) * 4;     // 0..60

  // compute coords
  const int ty = tid >> 4;  // 0..15 -> rows ty*8..+7
  const int tx = tid & 15;  // 0..15 -> cols tx*4..+3 and 64+tx*4..+3

  float acc[8][8];
#pragma unroll
  for (int i = 0; i < 8; ++i)
#pragma unroll
    for (int j = 0; j < 8; ++j) acc[i][j] = 0.f;

  for (int kt = 0; kt < 16; ++kt) {
    const int k0 = kt * 16;
    // global loads
    const float* Ap = A + (size_t)(bm + arow) * KA + kA0 + k0 + akl;
    float4 av0 = *(const float4*)(Ap);
    float4 av1 = *(const float4*)(Ap + 4);
    const float* Wp = Wbase + (size_t)(kW0 + k0 + bkrow) * H_ + bn + bnc;
    float4 bv0 = *(const float4*)(Wp);
    float4 bv1 = *(const float4*)(Wp + 64);

    __syncthreads();  // previous tile fully consumed
    As[akl + 0][arow] = av0.x; As[akl + 1][arow] = av0.y;
    As[akl + 2][arow] = av0.z; As[akl + 3][arow] = av0.w;
    As[akl + 4][arow] = av1.x; As[akl + 5][arow] = av1.y;
    As[akl + 6][arow] = av1.z; As[akl + 7][arow] = av1.w;
    *(float4*)&Bs[bkrow][bnc] = bv0;
    *(float4*)&Bs[bkrow][bnc + 64] = bv1;
    __syncthreads();

#pragma unroll
    for (int k = 0; k < 16; ++k) {
      float4 a0 = *(const float4*)&As[k][ty * 8];
      float4 a1 = *(const float4*)&As[k][ty * 8 + 4];
      float4 b0 = *(const float4*)&Bs[k][tx * 4];
      float4 b1 = *(const float4*)&Bs[k][tx * 4 + 64];
      float ar[8] = {a0.x, a0.y, a0.z, a0.w, a1.x, a1.y, a1.z, a1.w};
      float br[8] = {b0.x, b0.y, b0.z, b0.w, b1.x, b1.y, b1.z, b1.w};
#pragma unroll
      for (int i = 0; i < 8; ++i)
#pragma unroll
        for (int j = 0; j < 8; ++j) acc[i][j] += ar[i] * br[j];
    }
  }

  float* out = h1p + (size_t)z * (M_ROWS * (size_t)H_);
#pragma unroll
  for (int i = 0; i < 8; ++i) {
    int m = bm + ty * 8 + i;
    float* dst = out + (size_t)m * H_ + bn + tx * 4;
    *(float4*)dst = make_float4(acc[i][0], acc[i][1], acc[i][2], acc[i][3]);
    *(float4*)(dst + 64) = make_float4(acc[i][4], acc[i][5], acc[i][6], acc[i][7]);
  }
}

// Kernel 3: h0[b,:] = leaky(f0[b] @ Ws0 + m0[b] @ Wa0 + b0). 64 blocks x 256.
__global__ __launch_bounds__(256) void h0_kernel(
    const float* __restrict__ x, const float* __restrict__ m0,
    const float* __restrict__ Ws0, const float* __restrict__ Wa0,
    const float* __restrict__ b0, float* __restrict__ h0) {
  int b = blockIdx.x;
  int t = threadIdx.x;
  __shared__ float sf0[512];
  __shared__ float sm0[512];
  const float* xb = x + (size_t)b * L_ * D_;  // row 0 = f0
  sf0[t] = xb[t]; sf0[t + 256] = xb[t + 256];
  sm0[t] = m0[b * D_ + t]; sm0[t + 256] = m0[b * D_ + t + 256];
  __syncthreads();
  float acc0 = b0[t];
  float acc1 = b0[t + 256];
  for (int k = 0; k < 512; ++k) {
    float f = sf0[k], m = sm0[k];
    const float* ws = Ws0 + (size_t)k * H_;
    const float* wa = Wa0 + (size_t)k * H_;
    acc0 += f * ws[t] + m * wa[t];
    acc1 += f * ws[t + 256] + m * wa[t + 256];
  }
  h0[b * H_ + t] = leaky(acc0);
  h0[b * H_ + t + 256] = leaky(acc1);
}

// Kernel 4: mh1[b] = mean_f leaky(sum_z h1p + b0); out[b] = h0[b]@Ws1 + mh1[b]@Wa1 + b1
__global__ __launch_bounds__(256) void out_kernel(
    const float* __restrict__ h0, const float* __restrict__ h1p,
    const float* __restrict__ b0, const float* __restrict__ Ws1,
    const float* __restrict__ Wa1, const float* __restrict__ b1,
    float* __restrict__ out) {
  int b = blockIdx.x;
  int t = threadIdx.x;
  __shared__ float sh0[512];
  __shared__ float sm[512];
  sh0[t] = h0[b * H_ + t];
  sh0[t + 256] = h0[b * H_ + t + 256];
  const size_t P = (size_t)M_ROWS * H_;
  const float* hb = h1p + (size_t)b * F_ * H_;
  float bb0 = b0[t], bb1 = b0[t + 256];
  float acc0 = 0.f, acc1 = 0.f;
  for (int f = 0; f < 32; ++f) {
    size_t base = (size_t)f * H_;
    float v0 = hb[base + t] + hb[P + base + t] + hb[2 * P + base + t] +
               hb[3 * P + base + t] + bb0;
    float v1 = hb[base + t + 256] + hb[P + base + t + 256] +
               hb[2 * P + base + t + 256] + hb[3 * P + base + t + 256] + bb1;
    acc0 += leaky(v0);
    acc1 += leaky(v1);
  }
  sm[t] = acc0 * (1.0f / 32.0f);
  sm[t + 256] = acc1 * (1.0f / 32.0f);
  __syncthreads();
  float o0 = b1[t];
  float o1 = b1[t + 256];
  for (int k = 0; k < 512; ++k) {
    float h = sh0[k], m = sm[k];
    const float* ws = Ws1 + (size_t)k * H_;
    const float* wa = Wa1 + (size_t)k * H_;
    o0 += h * ws[t] + m * wa[t];
    o1 += h * ws[t + 256] + m * wa[t + 256];
  }
  out[b * H_ + t] = o0;
  out[b * H_ + t + 256] = o1;
}

extern "C" void kernel_launch(void* const* d_in, const int* in_sizes, int n_in,
                              void* d_out, int out_size, void* d_ws, size_t ws_size,
                              hipStream_t stream) {
  const float* x    = (const float*)d_in[0];
  const int*   idx1 = (const int*)d_in[1];
  const int*   idx2 = (const int*)d_in[2];
  const float* Wa0  = (const float*)d_in[3];
  const float* b0   = (const float*)d_in[4];
  const float* Ws0  = (const float*)d_in[5];
  const float* Wa1  = (const float*)d_in[6];
  const float* b1   = (const float*)d_in[7];
  const float* Ws1  = (const float*)d_in[8];
  float* out = (float*)d_out;

  float* ws  = (float*)d_ws;
  float* A   = ws;                        // 2048*1024
  float* m0  = A + (size_t)M_ROWS * KA;   // 64*512
  float* h1p = m0 + B_ * H_;              // 4 * 2048*512
  float* h0  = h1p + 4 * (size_t)M_ROWS * H_;  // 64*512

  gather_pack<<<M_ROWS + B_, 128, 0, stream>>>(x, idx1, idx2, A, m0);
  gemm_h1<<<dim3(16, 4, 4), 256, 0, stream>>>(A, Ws0, Wa0, h1p);
  h0_kernel<<<B_, 256, 0, stream>>>(x, m0, Ws0, Wa0, b0, h0);
  out_kernel<<<B_, 256, 0, stream>>>(h0, h1p, b0, Ws1, Wa1, b1, out);
}

// Round 3
// 77.972 us; speedup vs baseline: 1.8323x; 1.8323x over previous
//
#include <hip/hip_runtime.h>
#include <hip/hip_bf16.h>

// Shapes (compile-time constants from the reference)
#define B_ 64
#define L_ 64
#define D_ 512
#define F_ 32
#define H_ 512
#define M_ROWS 2048          // B*F_ neighbor rows
#define M2 2112              // + 64 [f0|m0] rows appended
#define KA 1024              // A row width: [f1|m1] or [f0|m0]

__device__ __forceinline__ float leaky(float v) { return v > 0.0f ? v : 0.01f * v; }

// Kernel 1: build A (2112 x 1024).
// rows 0..2047:  A[b*32+f] = [ x[b, idx1[b,f], :] | mean_j x[b, idx2[b,f*32+j], :] ]
// rows 2048..2111: A[2048+b] = [ x[b, 0, :] | mean_j x[b, idx1[b,j], :] ]
__global__ __launch_bounds__(128) void gather_pack(
    const float* __restrict__ x, const int* __restrict__ idx1,
    const int* __restrict__ idx2, float* __restrict__ A) {
  int blk = blockIdx.x;
  int t = threadIdx.x;  // col group: float4 at col t*4
  float* Arow = A + (size_t)blk * KA;
  if (blk < M_ROWS) {
    int b = blk >> 5;
    int f = blk & 31;
    const float* xb = x + (size_t)b * (L_ * D_);
    int r1 = idx1[b * F_ + f];
    *(float4*)(Arow + t * 4) = *(const float4*)(xb + (size_t)r1 * D_ + t * 4);
    const int* id2 = idx2 + (b * F_ + f) * F_;
    float4 acc = make_float4(0.f, 0.f, 0.f, 0.f);
#pragma unroll 4
    for (int j = 0; j < 32; ++j) {
      const float4 w = *(const float4*)(xb + (size_t)id2[j] * D_ + t * 4);
      acc.x += w.x; acc.y += w.y; acc.z += w.z; acc.w += w.w;
    }
    const float s = 1.0f / 32.0f;
    acc.x *= s; acc.y *= s; acc.z *= s; acc.w *= s;
    *(float4*)(Arow + D_ + t * 4) = acc;
  } else {
    int b = blk - M_ROWS;  // 0..63
    const float* xb = x + (size_t)b * (L_ * D_);
    *(float4*)(Arow + t * 4) = *(const float4*)(xb + t * 4);  // row 0 = f0
    const int* id1 = idx1 + b * F_;
    float4 acc = make_float4(0.f, 0.f, 0.f, 0.f);
#pragma unroll 4
    for (int j = 0; j < 32; ++j) {
      const float4 w = *(const float4*)(xb + (size_t)id1[j] * D_ + t * 4);
      acc.x += w.x; acc.y += w.y; acc.z += w.z; acc.w += w.w;
    }
    const float s = 1.0f / 32.0f;
    acc.x *= s; acc.y *= s; acc.z *= s; acc.w *= s;
    *(float4*)(Arow + D_ + t * 4) = acc;
  }
}

// Kernel 2: h1p[z] = A[:, z*256:(z+1)*256] @ Wpart(z). z in 0..3 (split-K).
// z=0,1 -> Ws0 rows (z&1)*256..; z=2,3 -> Wa0 rows (z&1)*256.. .
// Tile 64m x 128n, BK=16, 256 threads, 4x8 micro-tile. grid (33, 4, 4) = 528 blocks.
__global__ __launch_bounds__(256) void gemm_h1(
    const float* __restrict__ A, const float* __restrict__ Ws0,
    const float* __restrict__ Wa0, float* __restrict__ h1p) {
  __shared__ float As[16][68];    // [k][m], padded
  __shared__ float Bs[16][132];   // [k][n], padded
  const int tid = threadIdx.x;
  const int bm = blockIdx.x * 64;
  const int bn = blockIdx.y * 128;
  const int z = blockIdx.z;
  const float* Wbase = (z < 2) ? Ws0 : Wa0;
  const int kA0 = z * 256;
  const int kW0 = (z & 1) * 256;

  const int arow = tid >> 2;         // 0..63
  const int akl = (tid & 3) * 4;     // 0,4,8,12
  const int bkrow = tid >> 4;        // 0..15
  const int bnc = (tid & 15) * 4;    // 0..60

  const int tm = tid >> 4;  // 0..15 -> rows tm*4..+3
  const int tn = tid & 15;  // 0..15 -> cols tn*4..+3 and 64+tn*4..+3

  float acc[4][8];
#pragma unroll
  for (int i = 0; i < 4; ++i)
#pragma unroll
    for (int j = 0; j < 8; ++j) acc[i][j] = 0.f;

  for (int kt = 0; kt < 16; ++kt) {
    const int k0 = kt * 16;
    const float4 av = *(const float4*)(A + (size_t)(bm + arow) * KA + kA0 + k0 + akl);
    const float* Wp = Wbase + (size_t)(kW0 + k0 + bkrow) * H_ + bn + bnc;
    const float4 bv0 = *(const float4*)(Wp);
    const float4 bv1 = *(const float4*)(Wp + 64);

    __syncthreads();
    As[akl + 0][arow] = av.x;
    As[akl + 1][arow] = av.y;
    As[akl + 2][arow] = av.z;
    As[akl + 3][arow] = av.w;
    *(float4*)&Bs[bkrow][bnc] = bv0;
    *(float4*)&Bs[bkrow][bnc + 64] = bv1;
    __syncthreads();

#pragma unroll
    for (int k = 0; k < 16; ++k) {
      const float4 a = *(const float4*)&As[k][tm * 4];
      const float4 b0v = *(const float4*)&Bs[k][tn * 4];
      const float4 b1v = *(const float4*)&Bs[k][tn * 4 + 64];
      const float ar[4] = {a.x, a.y, a.z, a.w};
      const float br[8] = {b0v.x, b0v.y, b0v.z, b0v.w, b1v.x, b1v.y, b1v.z, b1v.w};
#pragma unroll
      for (int i = 0; i < 4; ++i)
#pragma unroll
        for (int j = 0; j < 8; ++j) acc[i][j] += ar[i] * br[j];
    }
  }

  float* outp = h1p + (size_t)z * ((size_t)M2 * H_);
#pragma unroll
  for (int i = 0; i < 4; ++i) {
    const int m = bm + tm * 4 + i;
    float* dst = outp + (size_t)m * H_ + bn + tn * 4;
    *(float4*)dst = make_float4(acc[i][0], acc[i][1], acc[i][2], acc[i][3]);
    *(float4*)(dst + 64) = make_float4(acc[i][4], acc[i][5], acc[i][6], acc[i][7]);
  }
}

// Kernel 3: hm[b] = [ h0[b] | mh1[b] ]  (64 x 1024)
//   h0[b,c]  = leaky(sum_z h1p[z][2048+b][c] + b0[c])
//   mh1[b,c] = (1/32) sum_f leaky(sum_z h1p[z][b*32+f][c] + b0[c])
// grid 256 = (b:64) x (col-group:4), 128 threads (col within group).
__global__ __launch_bounds__(128) void fuse_h(
    const float* __restrict__ h1p, const float* __restrict__ b0,
    float* __restrict__ hm) {
  const int blk = blockIdx.x;
  const int b = blk >> 2;
  const int g = blk & 3;
  const int c = g * 128 + threadIdx.x;
  const size_t P = (size_t)M2 * H_;
  const float bias = b0[c];

  const float* h0p = h1p + (size_t)(M_ROWS + b) * H_ + c;
  float s = h0p[0] + h0p[P] + h0p[2 * P] + h0p[3 * P] + bias;
  hm[(size_t)b * KA + c] = leaky(s);

  const float* basep = h1p + (size_t)(b * F_) * H_ + c;
  float acc = 0.f;
#pragma unroll 4
  for (int f = 0; f < 32; ++f) {
    const float* p = basep + (size_t)f * H_;
    float v = p[0] + p[P] + p[2 * P] + p[3 * P] + bias;
    acc += leaky(v);
  }
  hm[(size_t)b * KA + H_ + c] = acc * (1.0f / 32.0f);
}

// Kernel 4: part[kc] = hm[:, kc*128:+128] @ W2cat[kc*128:+128, :]
// W2cat rows 0..511 = Ws1, 512..1023 = Wa1. grid (16 n-tiles x 8 k-chunks), 256 thr.
__global__ __launch_bounds__(256) void gemm2(
    const float* __restrict__ hm, const float* __restrict__ Ws1,
    const float* __restrict__ Wa1, float* __restrict__ part) {
  __shared__ float lds[64][133];  // hm chunk [m][k], padded
  const int tid = threadIdx.x;
  const int n0 = blockIdx.x * 32;
  const int kc = blockIdx.y * 128;

#pragma unroll
  for (int i = 0; i < 8; ++i) {
    const int linear = i * 256 + tid;  // float4 index, 0..2047
    const int row = linear >> 5;       // 32 float4 per row
    const int c4 = (linear & 31) * 4;
    const float4 v = *(const float4*)(hm + (size_t)row * KA + kc + c4);
    lds[row][c4 + 0] = v.x;
    lds[row][c4 + 1] = v.y;
    lds[row][c4 + 2] = v.z;
    lds[row][c4 + 3] = v.w;
  }
  __syncthreads();

  const int col = n0 + (tid & 31);
  const int r0 = (tid >> 5) * 8;
  // kc-chunk lies entirely in one matrix (512 % 128 == 0)
  const float* W = (kc < 512) ? (Ws1 + (size_t)kc * H_)
                              : (Wa1 + (size_t)(kc - 512) * H_);
  float acc[8];
#pragma unroll
  for (int j = 0; j < 8; ++j) acc[j] = 0.f;

#pragma unroll 4
  for (int k = 0; k < 128; ++k) {
    const float w = W[(size_t)k * H_ + col];
#pragma unroll
    for (int j = 0; j < 8; ++j) acc[j] += lds[r0 + j][k] * w;
  }

  float* pp = part + (size_t)blockIdx.y * (B_ * H_);
#pragma unroll
  for (int j = 0; j < 8; ++j) pp[(size_t)(r0 + j) * H_ + col] = acc[j];
}

// Kernel 5: out = sum_k part[k] + b1. 64*512 floats = 8192 float4. grid 32 x 256.
__global__ __launch_bounds__(256) void reduce_out(
    const float* __restrict__ part, const float* __restrict__ b1,
    float* __restrict__ out) {
  const int idx = blockIdx.x * 256 + threadIdx.x;  // float4 index
  const int c4 = (idx & 127) * 4;                  // col
  const size_t off = (size_t)(idx >> 7) * H_ + c4;
  float4 s = *(const float4*)(b1 + c4);
#pragma unroll
  for (int k = 0; k < 8; ++k) {
    const float4 p = *(const float4*)(part + (size_t)k * (B_ * H_) + off);
    s.x += p.x; s.y += p.y; s.z += p.z; s.w += p.w;
  }
  *(float4*)(out + off) = s;
}

extern "C" void kernel_launch(void* const* d_in, const int* in_sizes, int n_in,
                              void* d_out, int out_size, void* d_ws, size_t ws_size,
                              hipStream_t stream) {
  const float* x    = (const float*)d_in[0];
  const int*   idx1 = (const int*)d_in[1];
  const int*   idx2 = (const int*)d_in[2];
  const float* Wa0  = (const float*)d_in[3];
  const float* b0   = (const float*)d_in[4];
  const float* Ws0  = (const float*)d_in[5];
  const float* Wa1  = (const float*)d_in[6];
  const float* b1   = (const float*)d_in[7];
  const float* Ws1  = (const float*)d_in[8];
  float* out = (float*)d_out;

  float* ws  = (float*)d_ws;
  float* A   = ws;                              // 2112*1024 = 8.65 MB
  float* h1p = A + (size_t)M2 * KA;             // 4*2112*512 = 17.3 MB
  // A region is dead after gemm_h1 -> reuse for hm and part (ordering on stream).
  float* hm   = A;                              // 64*1024
  float* part = A + (size_t)B_ * KA;            // 8*64*512

  gather_pack<<<M2, 128, 0, stream>>>(x, idx1, idx2, A);
  gemm_h1<<<dim3(33, 4, 4), 256, 0, stream>>>(A, Ws0, Wa0, h1p);
  fuse_h<<<B_ * 4, 128, 0, stream>>>(h1p, b0, hm);
  gemm2<<<dim3(16, 8), 256, 0, stream>>>(hm, Ws1, Wa1, part);
  reduce_out<<<32, 256, 0, stream>>>(part, b1, out);
}